// Round 1
// baseline (440.762 us; speedup 1.0000x reference)
//
#include <hip/hip_runtime.h>
#include <stdint.h>

// ---------- problem constants ----------
#define DIMC   512
#define NHEADS 16
#define HDIM   32
#define NWIN   64
#define NTOK   64
#define NBATCH 8
#define MROWS  (NBATCH * NWIN * NTOK)   // 32768

typedef unsigned short ushort_t;
typedef __attribute__((ext_vector_type(8))) short short8v;   // 8 bf16 = 4 VGPR
typedef __attribute__((ext_vector_type(4))) float f32x4;

__device__ inline ushort_t f2bf(float f) {           // round-to-nearest-even
    unsigned u = __float_as_uint(f);
    u += 0x7FFFu + ((u >> 16) & 1u);
    return (ushort_t)(u >> 16);
}
__device__ inline unsigned packbf2(float a, float b) {
    return ((unsigned)f2bf(a)) | (((unsigned)f2bf(b)) << 16);
}

// async global->LDS, 16B per lane; LDS dest is wave-uniform base + lane*16
#define G2L16(gp, lp) __builtin_amdgcn_global_load_lds( \
    (const __attribute__((address_space(1))) unsigned int*)(gp), \
    (__attribute__((address_space(3))) unsigned int*)(lp), 16, 0, 0)

// ---------- fp32 -> bf16 bulk convert (vectorized) ----------
__global__ __launch_bounds__(256) void cvt_f32_bf16(
    const float* __restrict__ in, ushort_t* __restrict__ out, int n4)
{
    int i = blockIdx.x * 256 + threadIdx.x;
    if (i < n4) {
        float4 v = reinterpret_cast<const float4*>(in)[i];
        ushort4 o;
        o.x = f2bf(v.x); o.y = f2bf(v.y); o.z = f2bf(v.z); o.w = f2bf(v.w);
        reinterpret_cast<ushort4*>(out)[i] = o;
    }
}

// ---------- qkv bias = concat[q_bias, 0, v_bias] ----------
__global__ void build_qkv_bias(const float* __restrict__ qb,
                               const float* __restrict__ vb,
                               float* __restrict__ bias)
{
    int i = blockIdx.x * 256 + threadIdx.x;
    if (i < 3 * DIMC) {
        float v = 0.f;
        if (i < DIMC) v = qb[i];
        else if (i >= 2 * DIMC) v = vb[i - 2 * DIMC];
        bias[i] = v;
    }
}

// ---------- bf16 MFMA GEMM, C[m,n] = sum_k A[m,k]*B[n,k] + bias[n] ----------
// m97-style: 128x128 block tile, BK=32, 4 waves (2x2), 16x16x32 MFMA.
template<bool OUT_BF16>
__global__ __launch_bounds__(256) void gemm_bt_128(
    const ushort_t* __restrict__ A, const ushort_t* __restrict__ B,
    const float* __restrict__ bias, void* __restrict__ C,
    int M, int N, int K)
{
    __shared__ ushort_t lsA[128 * 32];
    __shared__ ushort_t lsB[128 * 32];

    const int tid = threadIdx.x;
    const int l   = tid & 63;
    const int wv  = tid >> 6;        // wave id 0..3
    const int wr  = wv >> 1;         // wave row (2x2 wave grid)
    const int wc  = wv & 1;          // wave col
    const size_t mBase = (size_t)blockIdx.y * 128;
    const size_t nBase = (size_t)blockIdx.x * 128;

    f32x4 acc[4][4] = {};

    // staging addresses: per round r in {0,1}, a wave fills 16 rows x 32 cols
    const ushort_t* gA0 = A + (mBase + (size_t)(wv * 16 + (l >> 2))) * (size_t)K + (l & 3) * 8;
    const ushort_t* gB0 = B + (nBase + (size_t)(wv * 16 + (l >> 2))) * (size_t)K + (l & 3) * 8;
    ushort_t* lA0 = &lsA[(wv * 16) * 32];
    ushort_t* lB0 = &lsB[(wv * 16) * 32];
    const size_t rowStep = (size_t)64 * (size_t)K;   // 64 rows down for round 1

    for (int k0 = 0; k0 < K; k0 += 32) {
        G2L16(gA0 + k0,           lA0);
        G2L16(gA0 + k0 + rowStep, lA0 + 64 * 32);
        G2L16(gB0 + k0,           lB0);
        G2L16(gB0 + k0 + rowStep, lB0 + 64 * 32);
        __syncthreads();   // compiler drains vmcnt(0) before barrier

        short8v aF[4], bF[4];
        #pragma unroll
        for (int m = 0; m < 4; ++m)
            aF[m] = *reinterpret_cast<const short8v*>(
                &lsA[(wr * 64 + m * 16 + (l & 15)) * 32 + (l >> 4) * 8]);
        #pragma unroll
        for (int n = 0; n < 4; ++n)
            bF[n] = *reinterpret_cast<const short8v*>(
                &lsB[(wc * 64 + n * 16 + (l & 15)) * 32 + (l >> 4) * 8]);

        #pragma unroll
        for (int m = 0; m < 4; ++m)
            #pragma unroll
            for (int n = 0; n < 4; ++n)
                acc[m][n] = __builtin_amdgcn_mfma_f32_16x16x32_bf16(
                    aF[m], bF[n], acc[m][n], 0, 0, 0);
        __syncthreads();   // all ds_reads done before next stage overwrites
    }

    // epilogue: C/D layout col = lane&15, row = (lane>>4)*4 + i  [m89-verified]
    const int c0 = l & 15;
    const int r0 = (l >> 4) * 4;
    #pragma unroll
    for (int m = 0; m < 4; ++m) {
        #pragma unroll
        for (int n = 0; n < 4; ++n) {
            const size_t gn = nBase + (size_t)(wc * 64 + n * 16 + c0);
            const float bv = bias[gn];
            #pragma unroll
            for (int i = 0; i < 4; ++i) {
                const size_t gm = mBase + (size_t)(wr * 64 + m * 16 + r0 + i);
                const float val = acc[m][n][i] + bv;
                if (OUT_BF16) ((ushort_t*)C)[gm * (size_t)N + gn] = f2bf(val);
                else          ((float*)C)  [gm * (size_t)N + gn] = val;
            }
        }
    }
}

// ---------- fused cosine-norm + scale + axial RoPE + softmax + PV ----------
// one wave (64 threads) per (b, h, w) block; thread t = query row t.
__global__ __launch_bounds__(64) void win_attn(
    const ushort_t* __restrict__ qkv,          // [32768][1536] bf16
    const float* __restrict__ logit_scale,     // [16]
    ushort_t* __restrict__ attn_out)           // [32768][512]  bf16
{
    __shared__ float  kS[64][32];
    __shared__ float  vS[64][32];
    __shared__ float2 csT[8][8];   // (pos, freq) -> (cos, sin); shared for h/w axes

    const int t   = threadIdx.x;
    const int blk = blockIdx.x;
    const int w   = blk & 63;
    const int h   = (blk >> 6) & 15;
    const int b   = blk >> 10;

    // build cos/sin table: inv[f] = 10000^(-f/8)
    {
        const int pos = t >> 3, f = t & 7;
        const float inv = __expf(-(float)f * 1.1512925464970230f); // ln(10000)/8
        const float ang = (float)pos * inv;
        csT[pos][f] = make_float2(cosf(ang), sinf(ang));
    }

    const float sc = __expf(fmaxf(logit_scale[h], 4.6051701859880914f)); // clamp min ln(100)

    const size_t rowm = ((size_t)(b * 64 + w)) * 64 + (size_t)t;
    const ushort_t* base = qkv + rowm * 1536 + h * 32;

    float q[32], kk[32], vv[32];
    #pragma unroll
    for (int c = 0; c < 4; ++c) {
        uint4 uq = reinterpret_cast<const uint4*>(base)[c];
        uint4 uk = reinterpret_cast<const uint4*>(base + 512)[c];
        uint4 uv = reinterpret_cast<const uint4*>(base + 1024)[c];
        const unsigned aq[4] = {uq.x, uq.y, uq.z, uq.w};
        const unsigned ak[4] = {uk.x, uk.y, uk.z, uk.w};
        const unsigned av[4] = {uv.x, uv.y, uv.z, uv.w};
        #pragma unroll
        for (int j = 0; j < 4; ++j) {
            q [c*8 + j*2 + 0] = __uint_as_float((aq[j] & 0xFFFFu) << 16);
            q [c*8 + j*2 + 1] = __uint_as_float(aq[j] & 0xFFFF0000u);
            kk[c*8 + j*2 + 0] = __uint_as_float((ak[j] & 0xFFFFu) << 16);
            kk[c*8 + j*2 + 1] = __uint_as_float(ak[j] & 0xFFFF0000u);
            vv[c*8 + j*2 + 0] = __uint_as_float((av[j] & 0xFFFFu) << 16);
            vv[c*8 + j*2 + 1] = __uint_as_float(av[j] & 0xFFFF0000u);
        }
    }

    // L2 norms; fold logit scale and 1/sqrt(hd) into q
    float sq = 0.f, sk = 0.f;
    #pragma unroll
    for (int d = 0; d < 32; ++d) { sq += q[d] * q[d]; sk += kk[d] * kk[d]; }
    const float qsc = sc / fmaxf(sqrtf(sq), 1e-12f) * 0.17677669529663687f; // 1/sqrt(32)
    const float ksc = 1.0f / fmaxf(sqrtf(sk), 1e-12f);
    #pragma unroll
    for (int d = 0; d < 32; ++d) { q[d] *= qsc; kk[d] *= ksc; }

    __syncthreads();  // csT ready

    // axial RoPE: dims [0,16) rotate by wh-angles, [16,32) by ww-angles
    const int wh = t >> 3, ww = t & 7;
    #pragma unroll
    for (int p = 0; p < 8; ++p) {
        const float2 ch = csT[wh][p];
        float a0, a1;
        a0 = q [2*p]; a1 = q [2*p+1];
        q [2*p] = a0*ch.x - a1*ch.y;  q [2*p+1] = a1*ch.x + a0*ch.y;
        a0 = kk[2*p]; a1 = kk[2*p+1];
        kk[2*p] = a0*ch.x - a1*ch.y;  kk[2*p+1] = a1*ch.x + a0*ch.y;
        const float2 cw = csT[ww][p];
        a0 = q [16+2*p]; a1 = q [16+2*p+1];
        q [16+2*p] = a0*cw.x - a1*cw.y;  q [16+2*p+1] = a1*cw.x + a0*cw.y;
        a0 = kk[16+2*p]; a1 = kk[16+2*p+1];
        kk[16+2*p] = a0*cw.x - a1*cw.y;  kk[16+2*p+1] = a1*cw.x + a0*cw.y;
    }

    #pragma unroll
    for (int d = 0; d < 32; ++d) { kS[t][d] = kk[d]; vS[t][d] = vv[d]; }
    __syncthreads();

    // scores (broadcast LDS reads: all lanes read same kS[j][d] -> no conflict)
    float s_[64];
    #pragma unroll 8
    for (int j = 0; j < 64; ++j) {
        float acc = 0.f;
        #pragma unroll
        for (int d = 0; d < 32; ++d) acc += q[d] * kS[j][d];
        s_[j] = acc;
    }
    float mx = -1e30f;
    #pragma unroll
    for (int j = 0; j < 64; ++j) mx = fmaxf(mx, s_[j]);
    float ssum = 0.f;
    #pragma unroll
    for (int j = 0; j < 64; ++j) { s_[j] = __expf(s_[j] - mx); ssum += s_[j]; }
    const float isum = 1.0f / ssum;

    float o[32] = {};
    #pragma unroll 8
    for (int j = 0; j < 64; ++j) {
        const float pj = s_[j];
        #pragma unroll
        for (int d = 0; d < 32; ++d) o[d] += pj * vS[j][d];
    }

    ushort_t* op = attn_out + rowm * 512 + h * 32;
    #pragma unroll
    for (int c = 0; c < 4; ++c) {
        uint4 u;
        u.x = packbf2(o[c*8+0] * isum, o[c*8+1] * isum);
        u.y = packbf2(o[c*8+2] * isum, o[c*8+3] * isum);
        u.z = packbf2(o[c*8+4] * isum, o[c*8+5] * isum);
        u.w = packbf2(o[c*8+6] * isum, o[c*8+7] * isum);
        reinterpret_cast<uint4*>(op)[c] = u;
    }
}

// ---------- launch ----------
extern "C" void kernel_launch(void* const* d_in, const int* in_sizes, int n_in,
                              void* d_out, int out_size, void* d_ws, size_t ws_size,
                              hipStream_t stream)
{
    (void)in_sizes; (void)n_in; (void)out_size; (void)ws_size;
    const float* x     = (const float*)d_in[0];   // (8,64,64,512)
    const float* wqkv  = (const float*)d_in[1];   // (1536,512)
    const float* qb    = (const float*)d_in[2];   // (512)
    const float* vb    = (const float*)d_in[3];   // (512)
    const float* ls    = (const float*)d_in[4];   // (16,1,1,1)
    const float* wproj = (const float*)d_in[5];   // (512,512)
    const float* pb    = (const float*)d_in[6];   // (512)
    float* out = (float*)d_out;

    char* ws = (char*)d_ws;
    ushort_t* xb      = (ushort_t*)(ws);                    // 33,554,432 B
    ushort_t* wqkvb   = (ushort_t*)(ws + 33554432);         //  1,572,864 B
    ushort_t* wprojb  = (ushort_t*)(ws + 35127296);         //    524,288 B
    ushort_t* qkvb    = (ushort_t*)(ws + 35651584);         // 100,663,296 B
    ushort_t* attnb   = (ushort_t*)(ws + 136314880);        // 33,554,432 B
    float*    qkvbias = (float*)   (ws + 169869312);        //      6,144 B

    cvt_f32_bf16<<<16384, 256, 0, stream>>>(x,     xb,     16777216 / 4);
    cvt_f32_bf16<<<768,   256, 0, stream>>>(wqkv,  wqkvb,  786432   / 4);
    cvt_f32_bf16<<<256,   256, 0, stream>>>(wproj, wprojb, 262144   / 4);
    build_qkv_bias<<<6, 256, 0, stream>>>(qb, vb, qkvbias);

    // qkv = x @ Wqkv^T + bias   (M=32768, N=1536, K=512)
    gemm_bt_128<true><<<dim3(12, 256), 256, 0, stream>>>(
        xb, wqkvb, qkvbias, qkvb, MROWS, 3 * DIMC, DIMC);

    // per-window attention
    win_attn<<<NBATCH * NHEADS * NWIN, 64, 0, stream>>>(qkvb, ls, attnb);

    // out = attn @ Wproj^T + proj_bias   (M=32768, N=512, K=512), fp32 out
    gemm_bt_128<false><<<dim3(4, 256), 256, 0, stream>>>(
        attnb, wprojb, pb, out, MROWS, DIMC, DIMC);
}

// Round 2
// 276.654 us; speedup vs baseline: 1.5932x; 1.5932x over previous
//
#include <hip/hip_runtime.h>
#include <stdint.h>

// ---------- problem constants ----------
#define DIMC   512
#define NHEADS 16
#define HDIM   32
#define NWIN   64
#define NTOK   64
#define NBATCH 8
#define MROWS  (NBATCH * NWIN * NTOK)   // 32768

typedef unsigned short ushort_t;
typedef __attribute__((ext_vector_type(8))) short short8v;   // 8 bf16 = 4 VGPR
typedef __attribute__((ext_vector_type(4))) float f32x4;

__device__ inline ushort_t f2bf(float f) {           // round-to-nearest-even
    unsigned u = __float_as_uint(f);
    u += 0x7FFFu + ((u >> 16) & 1u);
    return (ushort_t)(u >> 16);
}
__device__ inline unsigned packbf2(float a, float b) {
    return ((unsigned)f2bf(a)) | (((unsigned)f2bf(b)) << 16);
}
__device__ inline void unpack8(uint4 u, float* f) {
    const unsigned a[4] = {u.x, u.y, u.z, u.w};
    #pragma unroll
    for (int j = 0; j < 4; ++j) {
        f[2*j+0] = __uint_as_float((a[j] & 0xFFFFu) << 16);
        f[2*j+1] = __uint_as_float(a[j] & 0xFFFF0000u);
    }
}

// async global->LDS, 16B per lane; LDS dest is wave-uniform base + lane*16
#define G2L16(gp, lp) __builtin_amdgcn_global_load_lds( \
    (const __attribute__((address_space(1))) unsigned int*)(gp), \
    (__attribute__((address_space(3))) unsigned int*)(lp), 16, 0, 0)

// ---------- fp32 -> bf16 bulk convert (vectorized) ----------
__global__ __launch_bounds__(256) void cvt_f32_bf16(
    const float* __restrict__ in, ushort_t* __restrict__ out, int n4)
{
    int i = blockIdx.x * 256 + threadIdx.x;
    if (i < n4) {
        float4 v = reinterpret_cast<const float4*>(in)[i];
        ushort4 o;
        o.x = f2bf(v.x); o.y = f2bf(v.y); o.z = f2bf(v.z); o.w = f2bf(v.w);
        reinterpret_cast<ushort4*>(out)[i] = o;
    }
}

// ---------- qkv bias = concat[q_bias, 0, v_bias] ----------
__global__ void build_qkv_bias(const float* __restrict__ qb,
                               const float* __restrict__ vb,
                               float* __restrict__ bias)
{
    int i = blockIdx.x * 256 + threadIdx.x;
    if (i < 3 * DIMC) {
        float v = 0.f;
        if (i < DIMC) v = qb[i];
        else if (i >= 2 * DIMC) v = vb[i - 2 * DIMC];
        bias[i] = v;
    }
}

// ---------- bf16 MFMA GEMM, C[m,n] = sum_k A[m,k]*B[n,k] + bias[n] ----------
template<bool OUT_BF16>
__global__ __launch_bounds__(256) void gemm_bt_128(
    const ushort_t* __restrict__ A, const ushort_t* __restrict__ B,
    const float* __restrict__ bias, void* __restrict__ C,
    int M, int N, int K)
{
    __shared__ ushort_t lsA[128 * 32];
    __shared__ ushort_t lsB[128 * 32];

    const int tid = threadIdx.x;
    const int l   = tid & 63;
    const int wv  = tid >> 6;        // wave id 0..3
    const int wr  = wv >> 1;         // wave row (2x2 wave grid)
    const int wc  = wv & 1;          // wave col
    const size_t mBase = (size_t)blockIdx.y * 128;
    const size_t nBase = (size_t)blockIdx.x * 128;

    f32x4 acc[4][4] = {};

    const ushort_t* gA0 = A + (mBase + (size_t)(wv * 16 + (l >> 2))) * (size_t)K + (l & 3) * 8;
    const ushort_t* gB0 = B + (nBase + (size_t)(wv * 16 + (l >> 2))) * (size_t)K + (l & 3) * 8;
    ushort_t* lA0 = &lsA[(wv * 16) * 32];
    ushort_t* lB0 = &lsB[(wv * 16) * 32];
    const size_t rowStep = (size_t)64 * (size_t)K;

    for (int k0 = 0; k0 < K; k0 += 32) {
        G2L16(gA0 + k0,           lA0);
        G2L16(gA0 + k0 + rowStep, lA0 + 64 * 32);
        G2L16(gB0 + k0,           lB0);
        G2L16(gB0 + k0 + rowStep, lB0 + 64 * 32);
        __syncthreads();

        short8v aF[4], bF[4];
        #pragma unroll
        for (int m = 0; m < 4; ++m)
            aF[m] = *reinterpret_cast<const short8v*>(
                &lsA[(wr * 64 + m * 16 + (l & 15)) * 32 + (l >> 4) * 8]);
        #pragma unroll
        for (int n = 0; n < 4; ++n)
            bF[n] = *reinterpret_cast<const short8v*>(
                &lsB[(wc * 64 + n * 16 + (l & 15)) * 32 + (l >> 4) * 8]);

        #pragma unroll
        for (int m = 0; m < 4; ++m)
            #pragma unroll
            for (int n = 0; n < 4; ++n)
                acc[m][n] = __builtin_amdgcn_mfma_f32_16x16x32_bf16(
                    aF[m], bF[n], acc[m][n], 0, 0, 0);
        __syncthreads();
    }

    const int c0 = l & 15;
    const int r0 = (l >> 4) * 4;
    #pragma unroll
    for (int m = 0; m < 4; ++m) {
        #pragma unroll
        for (int n = 0; n < 4; ++n) {
            const size_t gn = nBase + (size_t)(wc * 64 + n * 16 + c0);
            const float bv = bias[gn];
            #pragma unroll
            for (int i = 0; i < 4; ++i) {
                const size_t gm = mBase + (size_t)(wr * 64 + m * 16 + r0 + i);
                const float val = acc[m][n][i] + bv;
                if (OUT_BF16) ((ushort_t*)C)[gm * (size_t)N + gn] = f2bf(val);
                else          ((float*)C)  [gm * (size_t)N + gn] = val;
            }
        }
    }
}

// ---------- MFMA window attention: one wave per (b, h, w) ----------
// S^T = mfma(Kf, Qf) so P packs along k; out^T = mfma(Vf, Pf) so the
// epilogue packs along d and stores coalesced 64B rows.
__global__ __launch_bounds__(64, 3) void win_attn_mfma(
    const ushort_t* __restrict__ qkv,          // [32768][1536] bf16
    const float* __restrict__ logit_scale,     // [16]
    ushort_t* __restrict__ attn_out)           // [32768][512]  bf16
{
    __shared__ __align__(16) ushort_t lsP[64 * 64];   // P rows (swizzled); reused for out^T
    __shared__ __align__(16) ushort_t lsV[2 * 64 * 16]; // V halves [half][k][16]
    __shared__ float2 csT[8][8];                        // (pos, freqpair) -> (cos, sin)

    const int l = threadIdx.x;
    const int c = l & 15;          // frag row/col lane index
    const int g = l >> 4;          // k-chunk group 0..3
    const int blk = blockIdx.x;
    const int w = blk & 63;
    const int h = (blk >> 6) & 15;
    const int b = blk >> 10;
    const size_t R = ((size_t)(b * 64 + w)) * 64;      // first token row of window
    const ushort_t* qrow = qkv + R * 1536 + h * 32;

    // ---- issue V global->LDS early (linear LDS dest, strided global src) ----
    {
        const ushort_t* vbase = qrow + 1024;
        #pragma unroll
        for (int half = 0; half < 2; ++half)
            #pragma unroll
            for (int kg = 0; kg < 2; ++kg) {
                const ushort_t* gsrc = vbase + (size_t)(kg * 32 + (l >> 1)) * 1536
                                       + half * 16 + (l & 1) * 8;
                G2L16(gsrc, &lsV[half * 1024 + kg * 512]);
            }
    }

    // ---- cos/sin table: angle = pos * 10000^(-f/8) ----
    {
        const int pos = l >> 3, f = l & 7;
        const float inv = __expf(-(float)f * 1.1512925464970230f); // ln(10000)/8
        const float ang = (float)pos * inv;
        csT[pos][f] = make_float2(__cosf(ang), __sinf(ang));
    }

    const float sc = __expf(fmaxf(logit_scale[h], 4.6051701859880914f))
                     * 0.17677669529663687f;           // * 1/sqrt(32)

    // ---- load Q/K tiles, L2-norm (shfl), RoPE, pack bf16 frags ----
    short8v Qf[4], Kf[4];
    #pragma unroll
    for (int mi = 0; mi < 4; ++mi) {
        const int tok = mi * 16 + c;
        const ushort_t* qp = qrow + (size_t)tok * 1536 + g * 8;
        uint4 uq = *reinterpret_cast<const uint4*>(qp);
        uint4 uk = *reinterpret_cast<const uint4*>(qp + 512);
        float qv[8], kv[8];
        unpack8(uq, qv); unpack8(uk, kv);

        float sq = 0.f, sk = 0.f;
        #pragma unroll
        for (int d = 0; d < 8; ++d) { sq += qv[d] * qv[d]; sk += kv[d] * kv[d]; }
        sq += __shfl_xor(sq, 16); sq += __shfl_xor(sq, 32);   // full-row sumsq
        sk += __shfl_xor(sk, 16); sk += __shfl_xor(sk, 32);
        const float qs = sc * rsqrtf(fmaxf(sq, 1e-24f));
        const float ks =      rsqrtf(fmaxf(sk, 1e-24f));

        const int wh = tok >> 3, ww = tok & 7;
        const int axpos = (g >= 2) ? ww : wh;               // dims 16..31 use w-axis
        union { short8v v; unsigned u[4]; } pq, pk2;
        #pragma unroll
        for (int pp = 0; pp < 4; ++pp) {
            const float2 cs = csT[axpos][(g & 1) * 4 + pp];
            float a0 = qv[2*pp] * qs, a1 = qv[2*pp+1] * qs;
            const float q0 = a0 * cs.x - a1 * cs.y;
            const float q1 = a1 * cs.x + a0 * cs.y;
            a0 = kv[2*pp] * ks; a1 = kv[2*pp+1] * ks;
            const float k0 = a0 * cs.x - a1 * cs.y;
            const float k1 = a1 * cs.x + a0 * cs.y;
            pq.u[pp]  = packbf2(q0, q1);
            pk2.u[pp] = packbf2(k0, k1);
        }
        Qf[mi] = pq.v; Kf[mi] = pk2.v;
    }

    // ---- S^T = K · Q^T : tile (ki, qi); row=key, col=query ----
    f32x4 S[4][4];
    #pragma unroll
    for (int ki = 0; ki < 4; ++ki)
        #pragma unroll
        for (int qi = 0; qi < 4; ++qi)
            S[ki][qi] = __builtin_amdgcn_mfma_f32_16x16x32_bf16(
                Kf[ki], Qf[qi], (f32x4){0.f, 0.f, 0.f, 0.f}, 0, 0, 0);

    // ---- softmax per q-column (in-lane over ki,i + shfl over lane groups) ----
    float isum[4];
    #pragma unroll
    for (int qi = 0; qi < 4; ++qi) {
        float m = -1e30f;
        #pragma unroll
        for (int ki = 0; ki < 4; ++ki)
            #pragma unroll
            for (int i = 0; i < 4; ++i) m = fmaxf(m, S[ki][qi][i]);
        m = fmaxf(m, __shfl_xor(m, 16));
        m = fmaxf(m, __shfl_xor(m, 32));
        float sum = 0.f;
        #pragma unroll
        for (int ki = 0; ki < 4; ++ki)
            #pragma unroll
            for (int i = 0; i < 4; ++i) {
                const float p = __expf(S[ki][qi][i] - m);
                S[ki][qi][i] = p; sum += p;
            }
        sum += __shfl_xor(sum, 16); sum += __shfl_xor(sum, 32);
        isum[qi] = 1.0f / sum;
    }

    // ---- P -> LDS row-major [q][k] bf16, XOR-swizzled 16B slots ----
    #pragma unroll
    for (int qi = 0; qi < 4; ++qi) {
        const int q = qi * 16 + c;
        #pragma unroll
        for (int ki = 0; ki < 4; ++ki) {
            const int s2 = 2 * ki + (g >> 1);              // 16B slot of this b64
            const int byteoff = q * 128 + ((s2 ^ (q & 7)) * 16) + (g & 1) * 8;
            uint2 pk2;
            pk2.x = packbf2(S[ki][qi][0], S[ki][qi][1]);
            pk2.y = packbf2(S[ki][qi][2], S[ki][qi][3]);
            *reinterpret_cast<uint2*>(reinterpret_cast<char*>(lsP) + byteoff) = pk2;
        }
    }

    // ---- V frags (V^T rows): wait staging, scalar u16 gathers ----
    asm volatile("s_waitcnt vmcnt(0)" ::: "memory");
    short8v Vf[2][2];
    #pragma unroll
    for (int half = 0; half < 2; ++half)
        #pragma unroll
        for (int ki = 0; ki < 2; ++ki) {
            union { short8v v; ushort_t e[8]; } t;
            #pragma unroll
            for (int j = 0; j < 8; ++j)
                t.e[j] = lsV[half * 1024 + (ki * 32 + g * 8 + j) * 16 + c];
            Vf[half][ki] = t.v;
        }

    // ---- P frags (swizzled b128 reads) ----
    short8v Pf[4][2];
    #pragma unroll
    for (int ni = 0; ni < 4; ++ni) {
        const int q = ni * 16 + c;
        #pragma unroll
        for (int ki = 0; ki < 2; ++ki) {
            const int s2 = ki * 4 + g;
            Pf[ni][ki] = *reinterpret_cast<const short8v*>(
                reinterpret_cast<const char*>(lsP) + q * 128 + ((s2 ^ (q & 7)) * 16));
        }
    }

    // ---- out^T = V^T · P^T : tile (mi=d-half, ni=q-tile) ----
    f32x4 O[2][4];
    #pragma unroll
    for (int mi = 0; mi < 2; ++mi)
        #pragma unroll
        for (int ni = 0; ni < 4; ++ni) {
            f32x4 a = __builtin_amdgcn_mfma_f32_16x16x32_bf16(
                Vf[mi][0], Pf[ni][0], (f32x4){0.f, 0.f, 0.f, 0.f}, 0, 0, 0);
            O[mi][ni] = __builtin_amdgcn_mfma_f32_16x16x32_bf16(
                Vf[mi][1], Pf[ni][1], a, 0, 0, 0);
        }

    // ---- pack out rows (bf16, *isum) into reused lsP, swizzled ----
    #pragma unroll
    for (int ni = 0; ni < 4; ++ni) {
        const int q = ni * 16 + c;
        const float is = isum[ni];
        #pragma unroll
        for (int mi = 0; mi < 2; ++mi) {
            const int s = 2 * mi + (g >> 1);               // 16B slot in 64B row
            const int byteoff = q * 64 + ((s ^ (q & 3)) * 16) + (g & 1) * 8;
            uint2 pk2;
            pk2.x = packbf2(O[mi][ni][0] * is, O[mi][ni][1] * is);
            pk2.y = packbf2(O[mi][ni][2] * is, O[mi][ni][3] * is);
            *reinterpret_cast<uint2*>(reinterpret_cast<char*>(lsP) + byteoff) = pk2;
        }
    }

    // ---- coalesced store: lane reads chunk (q, p), stores 16B ----
    const int qr0 = l >> 2, p = l & 3;
    ushort_t* obase = attn_out + R * 512 + h * 32;
    #pragma unroll
    for (int r = 0; r < 4; ++r) {
        const int q = qr0 + r * 16;
        uint4 row = *reinterpret_cast<const uint4*>(
            reinterpret_cast<const char*>(lsP) + q * 64 + ((p ^ (q & 3)) * 16));
        *reinterpret_cast<uint4*>(
            reinterpret_cast<char*>(obase + (size_t)q * 512) + p * 16) = row;
    }
}

// ---------- launch ----------
extern "C" void kernel_launch(void* const* d_in, const int* in_sizes, int n_in,
                              void* d_out, int out_size, void* d_ws, size_t ws_size,
                              hipStream_t stream)
{
    (void)in_sizes; (void)n_in; (void)out_size; (void)ws_size;
    const float* x     = (const float*)d_in[0];   // (8,64,64,512)
    const float* wqkv  = (const float*)d_in[1];   // (1536,512)
    const float* qb    = (const float*)d_in[2];   // (512)
    const float* vb    = (const float*)d_in[3];   // (512)
    const float* ls    = (const float*)d_in[4];   // (16,1,1,1)
    const float* wproj = (const float*)d_in[5];   // (512,512)
    const float* pb    = (const float*)d_in[6];   // (512)
    float* out = (float*)d_out;

    char* ws = (char*)d_ws;
    ushort_t* xb      = (ushort_t*)(ws);                    // 33,554,432 B
    ushort_t* wqkvb   = (ushort_t*)(ws + 33554432);         //  1,572,864 B
    ushort_t* wprojb  = (ushort_t*)(ws + 35127296);         //    524,288 B
    ushort_t* qkvb    = (ushort_t*)(ws + 35651584);         // 100,663,296 B
    ushort_t* attnb   = (ushort_t*)(ws + 136314880);        // 33,554,432 B
    float*    qkvbias = (float*)   (ws + 169869312);        //      6,144 B

    cvt_f32_bf16<<<16384, 256, 0, stream>>>(x,     xb,     16777216 / 4);
    cvt_f32_bf16<<<768,   256, 0, stream>>>(wqkv,  wqkvb,  786432   / 4);
    cvt_f32_bf16<<<256,   256, 0, stream>>>(wproj, wprojb, 262144   / 4);
    build_qkv_bias<<<6, 256, 0, stream>>>(qb, vb, qkvbias);

    // qkv = x @ Wqkv^T + bias   (M=32768, N=1536, K=512)
    gemm_bt_128<true><<<dim3(12, 256), 256, 0, stream>>>(
        xb, wqkvb, qkvbias, qkvb, MROWS, 3 * DIMC, DIMC);

    // per-window attention (MFMA)
    win_attn_mfma<<<NBATCH * NHEADS * NWIN, 64, 0, stream>>>(qkvb, ls, attnb);

    // out = attn @ Wproj^T + proj_bias   (M=32768, N=512, K=512), fp32 out
    gemm_bt_128<false><<<dim3(4, 256), 256, 0, stream>>>(
        attnb, wprojb, pb, out, MROWS, DIMC, DIMC);
}

// Round 3
// 271.218 us; speedup vs baseline: 1.6251x; 1.0200x over previous
//
#include <hip/hip_runtime.h>
#include <stdint.h>

// ---------- problem constants ----------
#define DIMC   512
#define NHEADS 16
#define HDIM   32
#define NWIN   64
#define NTOK   64
#define NBATCH 8
#define MROWS  (NBATCH * NWIN * NTOK)   // 32768

typedef unsigned short ushort_t;
typedef __attribute__((ext_vector_type(8))) short short8v;   // 8 bf16 = 4 VGPR
typedef __attribute__((ext_vector_type(4))) float f32x4;

__device__ inline ushort_t f2bf(float f) {           // round-to-nearest-even
    unsigned u = __float_as_uint(f);
    u += 0x7FFFu + ((u >> 16) & 1u);
    return (ushort_t)(u >> 16);
}
__device__ inline unsigned packbf2(float a, float b) {
    return ((unsigned)f2bf(a)) | (((unsigned)f2bf(b)) << 16);
}
__device__ inline void unpack8(uint4 u, float* f) {
    const unsigned a[4] = {u.x, u.y, u.z, u.w};
    #pragma unroll
    for (int j = 0; j < 4; ++j) {
        f[2*j+0] = __uint_as_float((a[j] & 0xFFFFu) << 16);
        f[2*j+1] = __uint_as_float(a[j] & 0xFFFF0000u);
    }
}

// async global->LDS, 16B per lane; LDS dest is wave-uniform base + lane*16
#define G2L16(gp, lp) __builtin_amdgcn_global_load_lds( \
    (const __attribute__((address_space(1))) unsigned int*)(gp), \
    (__attribute__((address_space(3))) unsigned int*)(lp), 16, 0, 0)

// ---------- fp32 -> bf16 bulk convert (vectorized) ----------
__global__ __launch_bounds__(256) void cvt_f32_bf16(
    const float* __restrict__ in, ushort_t* __restrict__ out, int n4)
{
    int i = blockIdx.x * 256 + threadIdx.x;
    if (i < n4) {
        float4 v = reinterpret_cast<const float4*>(in)[i];
        ushort4 o;
        o.x = f2bf(v.x); o.y = f2bf(v.y); o.z = f2bf(v.z); o.w = f2bf(v.w);
        reinterpret_cast<ushort4*>(out)[i] = o;
    }
}

// ---------- qkv bias = concat[q_bias, 0, v_bias] ----------
__global__ void build_qkv_bias(const float* __restrict__ qb,
                               const float* __restrict__ vb,
                               float* __restrict__ bias)
{
    int i = blockIdx.x * 256 + threadIdx.x;
    if (i < 3 * DIMC) {
        float v = 0.f;
        if (i < DIMC) v = qb[i];
        else if (i >= 2 * DIMC) v = vb[i - 2 * DIMC];
        bias[i] = v;
    }
}

// ---------- bf16 MFMA GEMM, C[m,n] = sum_k A[m,k]*B[n,k] + bias[n] ----------
// 128x128 tile, BK=64, 4 waves (2x2), XOR-swizzled LDS (16B slots):
//   data of (row, chunk=col/8) lives at slot (chunk ^ (row&7)).
// Staging keeps the LDS dest linear (global_load_lds requirement) and
// pre-swizzles the per-lane GLOBAL source: lane l of an 8-row group fetches
// row (l>>3), chunk ((l&7) ^ (l>>3)).
template<bool OUT_BF16>
__global__ __launch_bounds__(256) void gemm_bt_128x64(
    const ushort_t* __restrict__ A, const ushort_t* __restrict__ B,
    const float* __restrict__ bias, void* __restrict__ C,
    int M, int N, int K)
{
    __shared__ ushort_t lsA[128 * 64];   // 16 KB
    __shared__ ushort_t lsB[128 * 64];   // 16 KB

    const int tid = threadIdx.x;
    const int l   = tid & 63;
    const int wv  = tid >> 6;        // wave id 0..3
    const int wr  = wv >> 1;         // wave row (2x2 wave grid)
    const int wc  = wv & 1;          // wave col
    const size_t mBase = (size_t)blockIdx.y * 128;
    const size_t nBase = (size_t)blockIdx.x * 128;

    f32x4 acc[4][4] = {};

    // staging geometry: wave wv covers rows wv*32 + j*8 .. +7 for j=0..3
    const int rl    = l >> 3;             // row within 8-row group
    const int chunk = (l & 7) ^ rl;       // pre-swizzled col-chunk (16B units)
    const ushort_t* gA0 = A + (mBase + (size_t)(wv * 32 + rl)) * (size_t)K + chunk * 8;
    const ushort_t* gB0 = B + (nBase + (size_t)(wv * 32 + rl)) * (size_t)K + chunk * 8;
    ushort_t* lA0 = &lsA[(wv * 32) * 64];
    ushort_t* lB0 = &lsB[(wv * 32) * 64];

    for (int k0 = 0; k0 < K; k0 += 64) {
        #pragma unroll
        for (int j = 0; j < 4; ++j) {
            G2L16(gA0 + (size_t)(j * 8) * (size_t)K + k0, lA0 + j * 8 * 64);
            G2L16(gB0 + (size_t)(j * 8) * (size_t)K + k0, lB0 + j * 8 * 64);
        }
        __syncthreads();   // vmcnt(0) drained by compiler before barrier

        #pragma unroll
        for (int kk = 0; kk < 2; ++kk) {
            short8v aF[4], bF[4];
            #pragma unroll
            for (int m = 0; m < 4; ++m) {
                const int row = wr * 64 + m * 16 + (l & 15);
                const int ps  = (kk * 4 + (l >> 4)) ^ (row & 7);
                aF[m] = *reinterpret_cast<const short8v*>(
                    reinterpret_cast<const char*>(lsA) + row * 128 + ps * 16);
            }
            #pragma unroll
            for (int n = 0; n < 4; ++n) {
                const int row = wc * 64 + n * 16 + (l & 15);
                const int ps  = (kk * 4 + (l >> 4)) ^ (row & 7);
                bF[n] = *reinterpret_cast<const short8v*>(
                    reinterpret_cast<const char*>(lsB) + row * 128 + ps * 16);
            }
            #pragma unroll
            for (int m = 0; m < 4; ++m)
                #pragma unroll
                for (int n = 0; n < 4; ++n)
                    acc[m][n] = __builtin_amdgcn_mfma_f32_16x16x32_bf16(
                        aF[m], bF[n], acc[m][n], 0, 0, 0);
        }
        __syncthreads();   // all ds_reads done before next stage overwrites
    }

    // epilogue: C/D layout col = lane&15, row = (lane>>4)*4 + i  [m89-verified]
    const int c0 = l & 15;
    const int r0 = (l >> 4) * 4;
    #pragma unroll
    for (int m = 0; m < 4; ++m) {
        #pragma unroll
        for (int n = 0; n < 4; ++n) {
            const size_t gn = nBase + (size_t)(wc * 64 + n * 16 + c0);
            const float bv = bias[gn];
            #pragma unroll
            for (int i = 0; i < 4; ++i) {
                const size_t gm = mBase + (size_t)(wr * 64 + m * 16 + r0 + i);
                const float val = acc[m][n][i] + bv;
                if (OUT_BF16) ((ushort_t*)C)[gm * (size_t)N + gn] = f2bf(val);
                else          ((float*)C)  [gm * (size_t)N + gn] = val;
            }
        }
    }
}

// ---------- MFMA window attention: one wave per (b, h, w) ----------
// S^T = mfma(Kf, Qf) so P packs along k; out^T = mfma(Vf, Pf) so the
// epilogue packs along d and stores coalesced 64B rows.
__global__ __launch_bounds__(64, 3) void win_attn_mfma(
    const ushort_t* __restrict__ qkv,          // [32768][1536] bf16
    const float* __restrict__ logit_scale,     // [16]
    ushort_t* __restrict__ attn_out)           // [32768][512]  bf16
{
    __shared__ __align__(16) ushort_t lsP[64 * 64];   // P rows (swizzled); reused for out^T
    __shared__ __align__(16) ushort_t lsV[2 * 64 * 16]; // V halves [half][k][16]
    __shared__ float2 csT[8][8];                        // (pos, freqpair) -> (cos, sin)

    const int l = threadIdx.x;
    const int c = l & 15;          // frag row/col lane index
    const int g = l >> 4;          // k-chunk group 0..3
    const int blk = blockIdx.x;
    const int w = blk & 63;
    const int h = (blk >> 6) & 15;
    const int b = blk >> 10;
    const size_t R = ((size_t)(b * 64 + w)) * 64;      // first token row of window
    const ushort_t* qrow = qkv + R * 1536 + h * 32;

    // ---- issue V global->LDS early (linear LDS dest, strided global src) ----
    {
        const ushort_t* vbase = qrow + 1024;
        #pragma unroll
        for (int half = 0; half < 2; ++half)
            #pragma unroll
            for (int kg = 0; kg < 2; ++kg) {
                const ushort_t* gsrc = vbase + (size_t)(kg * 32 + (l >> 1)) * 1536
                                       + half * 16 + (l & 1) * 8;
                G2L16(gsrc, &lsV[half * 1024 + kg * 512]);
            }
    }

    // ---- cos/sin table: angle = pos * 10000^(-f/8) ----
    {
        const int pos = l >> 3, f = l & 7;
        const float inv = __expf(-(float)f * 1.1512925464970230f); // ln(10000)/8
        const float ang = (float)pos * inv;
        csT[pos][f] = make_float2(__cosf(ang), __sinf(ang));
    }

    const float sc = __expf(fmaxf(logit_scale[h], 4.6051701859880914f))
                     * 0.17677669529663687f;           // * 1/sqrt(32)

    // ---- load Q/K tiles, L2-norm (shfl), RoPE, pack bf16 frags ----
    short8v Qf[4], Kf[4];
    #pragma unroll
    for (int mi = 0; mi < 4; ++mi) {
        const int tok = mi * 16 + c;
        const ushort_t* qp = qrow + (size_t)tok * 1536 + g * 8;
        uint4 uq = *reinterpret_cast<const uint4*>(qp);
        uint4 uk = *reinterpret_cast<const uint4*>(qp + 512);
        float qv[8], kv[8];
        unpack8(uq, qv); unpack8(uk, kv);

        float sq = 0.f, sk = 0.f;
        #pragma unroll
        for (int d = 0; d < 8; ++d) { sq += qv[d] * qv[d]; sk += kv[d] * kv[d]; }
        sq += __shfl_xor(sq, 16); sq += __shfl_xor(sq, 32);   // full-row sumsq
        sk += __shfl_xor(sk, 16); sk += __shfl_xor(sk, 32);
        const float qs = sc * rsqrtf(fmaxf(sq, 1e-24f));
        const float ks =      rsqrtf(fmaxf(sk, 1e-24f));

        const int wh = tok >> 3, ww = tok & 7;
        const int axpos = (g >= 2) ? ww : wh;               // dims 16..31 use w-axis
        union { short8v v; unsigned u[4]; } pq, pk2;
        #pragma unroll
        for (int pp = 0; pp < 4; ++pp) {
            const float2 cs = csT[axpos][(g & 1) * 4 + pp];
            float a0 = qv[2*pp] * qs, a1 = qv[2*pp+1] * qs;
            const float q0 = a0 * cs.x - a1 * cs.y;
            const float q1 = a1 * cs.x + a0 * cs.y;
            a0 = kv[2*pp] * ks; a1 = kv[2*pp+1] * ks;
            const float k0 = a0 * cs.x - a1 * cs.y;
            const float k1 = a1 * cs.x + a0 * cs.y;
            pq.u[pp]  = packbf2(q0, q1);
            pk2.u[pp] = packbf2(k0, k1);
        }
        Qf[mi] = pq.v; Kf[mi] = pk2.v;
    }

    // ---- S^T = K · Q^T : tile (ki, qi); row=key, col=query ----
    f32x4 S[4][4];
    #pragma unroll
    for (int ki = 0; ki < 4; ++ki)
        #pragma unroll
        for (int qi = 0; qi < 4; ++qi)
            S[ki][qi] = __builtin_amdgcn_mfma_f32_16x16x32_bf16(
                Kf[ki], Qf[qi], (f32x4){0.f, 0.f, 0.f, 0.f}, 0, 0, 0);

    // ---- softmax per q-column (in-lane over ki,i + shfl over lane groups) ----
    float isum[4];
    #pragma unroll
    for (int qi = 0; qi < 4; ++qi) {
        float m = -1e30f;
        #pragma unroll
        for (int ki = 0; ki < 4; ++ki)
            #pragma unroll
            for (int i = 0; i < 4; ++i) m = fmaxf(m, S[ki][qi][i]);
        m = fmaxf(m, __shfl_xor(m, 16));
        m = fmaxf(m, __shfl_xor(m, 32));
        float sum = 0.f;
        #pragma unroll
        for (int ki = 0; ki < 4; ++ki)
            #pragma unroll
            for (int i = 0; i < 4; ++i) {
                const float p = __expf(S[ki][qi][i] - m);
                S[ki][qi][i] = p; sum += p;
            }
        sum += __shfl_xor(sum, 16); sum += __shfl_xor(sum, 32);
        isum[qi] = 1.0f / sum;
    }

    // ---- P -> LDS row-major [q][k] bf16, XOR-swizzled 16B slots ----
    #pragma unroll
    for (int qi = 0; qi < 4; ++qi) {
        const int q = qi * 16 + c;
        #pragma unroll
        for (int ki = 0; ki < 4; ++ki) {
            const int s2 = 2 * ki + (g >> 1);              // 16B slot of this b64
            const int byteoff = q * 128 + ((s2 ^ (q & 7)) * 16) + (g & 1) * 8;
            uint2 pk2;
            pk2.x = packbf2(S[ki][qi][0], S[ki][qi][1]);
            pk2.y = packbf2(S[ki][qi][2], S[ki][qi][3]);
            *reinterpret_cast<uint2*>(reinterpret_cast<char*>(lsP) + byteoff) = pk2;
        }
    }

    // ---- V frags (V^T rows): wait staging, scalar u16 gathers ----
    asm volatile("s_waitcnt vmcnt(0)" ::: "memory");
    short8v Vf[2][2];
    #pragma unroll
    for (int half = 0; half < 2; ++half)
        #pragma unroll
        for (int ki = 0; ki < 2; ++ki) {
            union { short8v v; ushort_t e[8]; } t;
            #pragma unroll
            for (int j = 0; j < 8; ++j)
                t.e[j] = lsV[half * 1024 + (ki * 32 + g * 8 + j) * 16 + c];
            Vf[half][ki] = t.v;
        }

    // ---- P frags (swizzled b128 reads) ----
    short8v Pf[4][2];
    #pragma unroll
    for (int ni = 0; ni < 4; ++ni) {
        const int q = ni * 16 + c;
        #pragma unroll
        for (int ki = 0; ki < 2; ++ki) {
            const int s2 = ki * 4 + g;
            Pf[ni][ki] = *reinterpret_cast<const short8v*>(
                reinterpret_cast<const char*>(lsP) + q * 128 + ((s2 ^ (q & 7)) * 16));
        }
    }

    // ---- out^T = V^T · P^T : tile (mi=d-half, ni=q-tile) ----
    f32x4 O[2][4];
    #pragma unroll
    for (int mi = 0; mi < 2; ++mi)
        #pragma unroll
        for (int ni = 0; ni < 4; ++ni) {
            f32x4 a = __builtin_amdgcn_mfma_f32_16x16x32_bf16(
                Vf[mi][0], Pf[ni][0], (f32x4){0.f, 0.f, 0.f, 0.f}, 0, 0, 0);
            O[mi][ni] = __builtin_amdgcn_mfma_f32_16x16x32_bf16(
                Vf[mi][1], Pf[ni][1], a, 0, 0, 0);
        }

    // ---- pack out rows (bf16, *isum) into reused lsP, swizzled ----
    #pragma unroll
    for (int ni = 0; ni < 4; ++ni) {
        const int q = ni * 16 + c;
        const float is = isum[ni];
        #pragma unroll
        for (int mi = 0; mi < 2; ++mi) {
            const int s = 2 * mi + (g >> 1);               // 16B slot in 64B row
            const int byteoff = q * 64 + ((s ^ (q & 3)) * 16) + (g & 1) * 8;
            uint2 pk2;
            pk2.x = packbf2(O[mi][ni][0] * is, O[mi][ni][1] * is);
            pk2.y = packbf2(O[mi][ni][2] * is, O[mi][ni][3] * is);
            *reinterpret_cast<uint2*>(reinterpret_cast<char*>(lsP) + byteoff) = pk2;
        }
    }

    // ---- coalesced store: lane reads chunk (q, p), stores 16B ----
    const int qr0 = l >> 2, p = l & 3;
    ushort_t* obase = attn_out + R * 512 + h * 32;
    #pragma unroll
    for (int r = 0; r < 4; ++r) {
        const int q = qr0 + r * 16;
        uint4 row = *reinterpret_cast<const uint4*>(
            reinterpret_cast<const char*>(lsP) + q * 64 + ((p ^ (q & 3)) * 16));
        *reinterpret_cast<uint4*>(
            reinterpret_cast<char*>(obase + (size_t)q * 512) + p * 16) = row;
    }
}

// ---------- launch ----------
extern "C" void kernel_launch(void* const* d_in, const int* in_sizes, int n_in,
                              void* d_out, int out_size, void* d_ws, size_t ws_size,
                              hipStream_t stream)
{
    (void)in_sizes; (void)n_in; (void)out_size; (void)ws_size;
    const float* x     = (const float*)d_in[0];   // (8,64,64,512)
    const float* wqkv  = (const float*)d_in[1];   // (1536,512)
    const float* qb    = (const float*)d_in[2];   // (512)
    const float* vb    = (const float*)d_in[3];   // (512)
    const float* ls    = (const float*)d_in[4];   // (16,1,1,1)
    const float* wproj = (const float*)d_in[5];   // (512,512)
    const float* pb    = (const float*)d_in[6];   // (512)
    float* out = (float*)d_out;

    char* ws = (char*)d_ws;
    ushort_t* xb      = (ushort_t*)(ws);                    // 33,554,432 B
    ushort_t* wqkvb   = (ushort_t*)(ws + 33554432);         //  1,572,864 B
    ushort_t* wprojb  = (ushort_t*)(ws + 35127296);         //    524,288 B
    ushort_t* qkvb    = (ushort_t*)(ws + 35651584);         // 100,663,296 B
    ushort_t* attnb   = (ushort_t*)(ws + 136314880);        // 33,554,432 B
    float*    qkvbias = (float*)   (ws + 169869312);        //      6,144 B

    cvt_f32_bf16<<<16384, 256, 0, stream>>>(x,     xb,     16777216 / 4);
    cvt_f32_bf16<<<768,   256, 0, stream>>>(wqkv,  wqkvb,  786432   / 4);
    cvt_f32_bf16<<<256,   256, 0, stream>>>(wproj, wprojb, 262144   / 4);
    build_qkv_bias<<<6, 256, 0, stream>>>(qb, vb, qkvbias);

    // qkv = x @ Wqkv^T + bias   (M=32768, N=1536, K=512)
    gemm_bt_128x64<true><<<dim3(12, 256), 256, 0, stream>>>(
        xb, wqkvb, qkvbias, qkvb, MROWS, 3 * DIMC, DIMC);

    // per-window attention (MFMA)
    win_attn_mfma<<<NBATCH * NHEADS * NWIN, 64, 0, stream>>>(qkvb, ls, attnb);

    // out = attn @ Wproj^T + proj_bias   (M=32768, N=512, K=512), fp32 out
    gemm_bt_128x64<false><<<dim3(4, 256), 256, 0, stream>>>(
        attnb, wprojb, pb, out, MROWS, DIMC, DIMC);
}

// Round 4
// 259.860 us; speedup vs baseline: 1.6961x; 1.0437x over previous
//
#include <hip/hip_runtime.h>
#include <stdint.h>

// ---------- problem constants ----------
#define DIMC   512
#define NHEADS 16
#define HDIM   32
#define NWIN   64
#define NTOK   64
#define NBATCH 8
#define MROWS  (NBATCH * NWIN * NTOK)   // 32768

typedef unsigned short ushort_t;
typedef __attribute__((ext_vector_type(8))) short short8v;   // 8 bf16 = 4 VGPR
typedef __attribute__((ext_vector_type(4))) float f32x4;

__device__ inline ushort_t f2bf(float f) {           // round-to-nearest-even
    unsigned u = __float_as_uint(f);
    u += 0x7FFFu + ((u >> 16) & 1u);
    return (ushort_t)(u >> 16);
}
__device__ inline unsigned packbf2(float a, float b) {
    return ((unsigned)f2bf(a)) | (((unsigned)f2bf(b)) << 16);
}
__device__ inline void unpack8(uint4 u, float* f) {
    const unsigned a[4] = {u.x, u.y, u.z, u.w};
    #pragma unroll
    for (int j = 0; j < 4; ++j) {
        f[2*j+0] = __uint_as_float((a[j] & 0xFFFFu) << 16);
        f[2*j+1] = __uint_as_float(a[j] & 0xFFFF0000u);
    }
}

// async global->LDS, 16B per lane; LDS dest is wave-uniform base + lane*16
#define G2L16(gp, lp) __builtin_amdgcn_global_load_lds( \
    (const __attribute__((address_space(1))) unsigned int*)(gp), \
    (__attribute__((address_space(3))) unsigned int*)(lp), 16, 0, 0)

// ---------- fp32 -> bf16 bulk convert (vectorized) ----------
__global__ __launch_bounds__(256) void cvt_f32_bf16(
    const float* __restrict__ in, ushort_t* __restrict__ out, int n4)
{
    int i = blockIdx.x * 256 + threadIdx.x;
    if (i < n4) {
        float4 v = reinterpret_cast<const float4*>(in)[i];
        ushort4 o;
        o.x = f2bf(v.x); o.y = f2bf(v.y); o.z = f2bf(v.z); o.w = f2bf(v.w);
        reinterpret_cast<ushort4*>(out)[i] = o;
    }
}

// ---------- qkv bias = concat[q_bias, 0, v_bias] ----------
__global__ void build_qkv_bias(const float* __restrict__ qb,
                               const float* __restrict__ vb,
                               float* __restrict__ bias)
{
    int i = blockIdx.x * 256 + threadIdx.x;
    if (i < 3 * DIMC) {
        float v = 0.f;
        if (i < DIMC) v = qb[i];
        else if (i >= 2 * DIMC) v = vb[i - 2 * DIMC];
        bias[i] = v;
    }
}

// ---------- bf16 MFMA GEMM, C[m,n] = sum_k A[m,k]*B[n,k] + bias[n] ----------
// 128x128 tile, BK=64, 4 waves (2x2). 2-phase double-buffered LDS:
// STAGE(t+1) issued BEFORE compute(t), single barrier per K-step, so the
// global_load_lds latency hides under the 32 MFMAs. XOR-swizzled LDS
// (16B slots): data (row, chunk) at slot (chunk ^ (row&7)); staging keeps
// LDS dest linear and pre-swizzles the per-lane GLOBAL source.
// Grid is 1-D with bijective XCD swizzle (requires gridDim.x % 8 == 0):
// each XCD gets a contiguous chunk of tiles so the nx blocks sharing an
// A-panel co-reside on one XCD's L2.
template<bool OUT_BF16>
__global__ __launch_bounds__(256) void gemm_bt_2ph(
    const ushort_t* __restrict__ A, const ushort_t* __restrict__ B,
    const float* __restrict__ bias, void* __restrict__ C,
    int M, int N, int K, int nx)
{
    __shared__ ushort_t lsA[2][128 * 64];   // 32 KB
    __shared__ ushort_t lsB[2][128 * 64];   // 32 KB

    const int tid = threadIdx.x;
    const int l   = tid & 63;
    const int wv  = tid >> 6;        // wave id 0..3
    const int wr  = wv >> 1;         // wave row (2x2 wave grid)
    const int wc  = wv & 1;          // wave col

    // XCD-aware swizzle: orig%8 = XCD; give each XCD a contiguous tile chunk
    const int nwg = (int)gridDim.x;
    const int bid = (int)blockIdx.x;
    const int swz = (bid & 7) * (nwg >> 3) + (bid >> 3);
    const size_t mBase = (size_t)(swz / nx) * 128;
    const size_t nBase = (size_t)(swz % nx) * 128;

    f32x4 acc[4][4] = {};

    // staging geometry: wave wv covers rows wv*32 + j*8 .. +7, j=0..3
    const int rl    = l >> 3;             // row within 8-row group
    const int chunk = (l & 7) ^ rl;       // pre-swizzled col-chunk (16B units)
    const ushort_t* gA0 = A + (mBase + (size_t)(wv * 32 + rl)) * (size_t)K + chunk * 8;
    const ushort_t* gB0 = B + (nBase + (size_t)(wv * 32 + rl)) * (size_t)K + chunk * 8;

    auto STAGE = [&](int buf, int t) {
        const int k0 = t << 6;
        #pragma unroll
        for (int j = 0; j < 4; ++j) {
            G2L16(gA0 + (size_t)(j * 8) * (size_t)K + k0,
                  &lsA[buf][(wv * 32 + j * 8) * 64]);
            G2L16(gB0 + (size_t)(j * 8) * (size_t)K + k0,
                  &lsB[buf][(wv * 32 + j * 8) * 64]);
        }
    };

    auto COMPUTE = [&](int buf) {
        #pragma unroll
        for (int kk = 0; kk < 2; ++kk) {
            short8v aF[4], bF[4];
            #pragma unroll
            for (int m = 0; m < 4; ++m) {
                const int row = wr * 64 + m * 16 + (l & 15);
                const int ps  = (kk * 4 + (l >> 4)) ^ (row & 7);
                aF[m] = *reinterpret_cast<const short8v*>(
                    reinterpret_cast<const char*>(lsA[buf]) + row * 128 + ps * 16);
            }
            #pragma unroll
            for (int n = 0; n < 4; ++n) {
                const int row = wc * 64 + n * 16 + (l & 15);
                const int ps  = (kk * 4 + (l >> 4)) ^ (row & 7);
                bF[n] = *reinterpret_cast<const short8v*>(
                    reinterpret_cast<const char*>(lsB[buf]) + row * 128 + ps * 16);
            }
            #pragma unroll
            for (int m = 0; m < 4; ++m)
                #pragma unroll
                for (int n = 0; n < 4; ++n)
                    acc[m][n] = __builtin_amdgcn_mfma_f32_16x16x32_bf16(
                        aF[m], bF[n], acc[m][n], 0, 0, 0);
        }
    };

    const int nt = K >> 6;           // K-tiles
    STAGE(0, 0);
    __syncthreads();                 // drains vmcnt(0): tile 0 resident
    int cur = 0;
    for (int t = 0; t < nt - 1; ++t) {
        STAGE(cur ^ 1, t + 1);       // issue next tile early
        COMPUTE(cur);                // MFMA hides the staging latency
        __syncthreads();             // drains stage(t+1) + this tile's ds_reads
        cur ^= 1;
    }
    COMPUTE(cur);                    // last tile, no prefetch

    // epilogue: C/D layout col = lane&15, row = (lane>>4)*4 + i  [m89-verified]
    const int c0 = l & 15;
    const int r0 = (l >> 4) * 4;
    #pragma unroll
    for (int m = 0; m < 4; ++m) {
        #pragma unroll
        for (int n = 0; n < 4; ++n) {
            const size_t gn = nBase + (size_t)(wc * 64 + n * 16 + c0);
            const float bv = bias[gn];
            #pragma unroll
            for (int i = 0; i < 4; ++i) {
                const size_t gm = mBase + (size_t)(wr * 64 + m * 16 + r0 + i);
                const float val = acc[m][n][i] + bv;
                if (OUT_BF16) ((ushort_t*)C)[gm * (size_t)N + gn] = f2bf(val);
                else          ((float*)C)  [gm * (size_t)N + gn] = val;
            }
        }
    }
}

// ---------- MFMA window attention: one wave per (b, h, w) ----------
// S^T = mfma(Kf, Qf) so P packs along k; out^T = mfma(Vf, Pf) so the
// epilogue packs along d and stores coalesced 64B rows.
__global__ __launch_bounds__(64, 3) void win_attn_mfma(
    const ushort_t* __restrict__ qkv,          // [32768][1536] bf16
    const float* __restrict__ logit_scale,     // [16]
    ushort_t* __restrict__ attn_out)           // [32768][512]  bf16
{
    __shared__ __align__(16) ushort_t lsP[64 * 64];   // P rows (swizzled); reused for out^T
    __shared__ __align__(16) ushort_t lsV[2 * 64 * 16]; // V halves [half][k][16]
    __shared__ float2 csT[8][8];                        // (pos, freqpair) -> (cos, sin)

    const int l = threadIdx.x;
    const int c = l & 15;          // frag row/col lane index
    const int g = l >> 4;          // k-chunk group 0..3
    const int blk = blockIdx.x;
    const int w = blk & 63;
    const int h = (blk >> 6) & 15;
    const int b = blk >> 10;
    const size_t R = ((size_t)(b * 64 + w)) * 64;      // first token row of window
    const ushort_t* qrow = qkv + R * 1536 + h * 32;

    // ---- issue V global->LDS early (linear LDS dest, strided global src) ----
    {
        const ushort_t* vbase = qrow + 1024;
        #pragma unroll
        for (int half = 0; half < 2; ++half)
            #pragma unroll
            for (int kg = 0; kg < 2; ++kg) {
                const ushort_t* gsrc = vbase + (size_t)(kg * 32 + (l >> 1)) * 1536
                                       + half * 16 + (l & 1) * 8;
                G2L16(gsrc, &lsV[half * 1024 + kg * 512]);
            }
    }

    // ---- cos/sin table: angle = pos * 10000^(-f/8) ----
    {
        const int pos = l >> 3, f = l & 7;
        const float inv = __expf(-(float)f * 1.1512925464970230f); // ln(10000)/8
        const float ang = (float)pos * inv;
        csT[pos][f] = make_float2(__cosf(ang), __sinf(ang));
    }

    const float sc = __expf(fmaxf(logit_scale[h], 4.6051701859880914f))
                     * 0.17677669529663687f;           // * 1/sqrt(32)

    // ---- load Q/K tiles, L2-norm (shfl), RoPE, pack bf16 frags ----
    short8v Qf[4], Kf[4];
    #pragma unroll
    for (int mi = 0; mi < 4; ++mi) {
        const int tok = mi * 16 + c;
        const ushort_t* qp = qrow + (size_t)tok * 1536 + g * 8;
        uint4 uq = *reinterpret_cast<const uint4*>(qp);
        uint4 uk = *reinterpret_cast<const uint4*>(qp + 512);
        float qv[8], kv[8];
        unpack8(uq, qv); unpack8(uk, kv);

        float sq = 0.f, sk = 0.f;
        #pragma unroll
        for (int d = 0; d < 8; ++d) { sq += qv[d] * qv[d]; sk += kv[d] * kv[d]; }
        sq += __shfl_xor(sq, 16); sq += __shfl_xor(sq, 32);   // full-row sumsq
        sk += __shfl_xor(sk, 16); sk += __shfl_xor(sk, 32);
        const float qs = sc * rsqrtf(fmaxf(sq, 1e-24f));
        const float ks =      rsqrtf(fmaxf(sk, 1e-24f));

        const int wh = tok >> 3, ww = tok & 7;
        const int axpos = (g >= 2) ? ww : wh;               // dims 16..31 use w-axis
        union { short8v v; unsigned u[4]; } pq, pk2;
        #pragma unroll
        for (int pp = 0; pp < 4; ++pp) {
            const float2 cs = csT[axpos][(g & 1) * 4 + pp];
            float a0 = qv[2*pp] * qs, a1 = qv[2*pp+1] * qs;
            const float q0 = a0 * cs.x - a1 * cs.y;
            const float q1 = a1 * cs.x + a0 * cs.y;
            a0 = kv[2*pp] * ks; a1 = kv[2*pp+1] * ks;
            const float k0 = a0 * cs.x - a1 * cs.y;
            const float k1 = a1 * cs.x + a0 * cs.y;
            pq.u[pp]  = packbf2(q0, q1);
            pk2.u[pp] = packbf2(k0, k1);
        }
        Qf[mi] = pq.v; Kf[mi] = pk2.v;
    }

    // ---- S^T = K · Q^T : tile (ki, qi); row=key, col=query ----
    f32x4 S[4][4];
    #pragma unroll
    for (int ki = 0; ki < 4; ++ki)
        #pragma unroll
        for (int qi = 0; qi < 4; ++qi)
            S[ki][qi] = __builtin_amdgcn_mfma_f32_16x16x32_bf16(
                Kf[ki], Qf[qi], (f32x4){0.f, 0.f, 0.f, 0.f}, 0, 0, 0);

    // ---- softmax per q-column (in-lane over ki,i + shfl over lane groups) ----
    float isum[4];
    #pragma unroll
    for (int qi = 0; qi < 4; ++qi) {
        float m = -1e30f;
        #pragma unroll
        for (int ki = 0; ki < 4; ++ki)
            #pragma unroll
            for (int i = 0; i < 4; ++i) m = fmaxf(m, S[ki][qi][i]);
        m = fmaxf(m, __shfl_xor(m, 16));
        m = fmaxf(m, __shfl_xor(m, 32));
        float sum = 0.f;
        #pragma unroll
        for (int ki = 0; ki < 4; ++ki)
            #pragma unroll
            for (int i = 0; i < 4; ++i) {
                const float p = __expf(S[ki][qi][i] - m);
                S[ki][qi][i] = p; sum += p;
            }
        sum += __shfl_xor(sum, 16); sum += __shfl_xor(sum, 32);
        isum[qi] = 1.0f / sum;
    }

    // ---- P -> LDS row-major [q][k] bf16, XOR-swizzled 16B slots ----
    #pragma unroll
    for (int qi = 0; qi < 4; ++qi) {
        const int q = qi * 16 + c;
        #pragma unroll
        for (int ki = 0; ki < 4; ++ki) {
            const int s2 = 2 * ki + (g >> 1);              // 16B slot of this b64
            const int byteoff = q * 128 + ((s2 ^ (q & 7)) * 16) + (g & 1) * 8;
            uint2 pk2;
            pk2.x = packbf2(S[ki][qi][0], S[ki][qi][1]);
            pk2.y = packbf2(S[ki][qi][2], S[ki][qi][3]);
            *reinterpret_cast<uint2*>(reinterpret_cast<char*>(lsP) + byteoff) = pk2;
        }
    }

    // ---- V frags (V^T rows): wait staging, scalar u16 gathers ----
    asm volatile("s_waitcnt vmcnt(0)" ::: "memory");
    short8v Vf[2][2];
    #pragma unroll
    for (int half = 0; half < 2; ++half)
        #pragma unroll
        for (int ki = 0; ki < 2; ++ki) {
            union { short8v v; ushort_t e[8]; } t;
            #pragma unroll
            for (int j = 0; j < 8; ++j)
                t.e[j] = lsV[half * 1024 + (ki * 32 + g * 8 + j) * 16 + c];
            Vf[half][ki] = t.v;
        }

    // ---- P frags (swizzled b128 reads) ----
    short8v Pf[4][2];
    #pragma unroll
    for (int ni = 0; ni < 4; ++ni) {
        const int q = ni * 16 + c;
        #pragma unroll
        for (int ki = 0; ki < 2; ++ki) {
            const int s2 = ki * 4 + g;
            Pf[ni][ki] = *reinterpret_cast<const short8v*>(
                reinterpret_cast<const char*>(lsP) + q * 128 + ((s2 ^ (q & 7)) * 16));
        }
    }

    // ---- out^T = V^T · P^T : tile (mi=d-half, ni=q-tile) ----
    f32x4 O[2][4];
    #pragma unroll
    for (int mi = 0; mi < 2; ++mi)
        #pragma unroll
        for (int ni = 0; ni < 4; ++ni) {
            f32x4 a = __builtin_amdgcn_mfma_f32_16x16x32_bf16(
                Vf[mi][0], Pf[ni][0], (f32x4){0.f, 0.f, 0.f, 0.f}, 0, 0, 0);
            O[mi][ni] = __builtin_amdgcn_mfma_f32_16x16x32_bf16(
                Vf[mi][1], Pf[ni][1], a, 0, 0, 0);
        }

    // ---- pack out rows (bf16, *isum) into reused lsP, swizzled ----
    __syncthreads();
    #pragma unroll
    for (int ni = 0; ni < 4; ++ni) {
        const int q = ni * 16 + c;
        const float is = isum[ni];
        #pragma unroll
        for (int mi = 0; mi < 2; ++mi) {
            const int s = 2 * mi + (g >> 1);               // 16B slot in 64B row
            const int byteoff = q * 64 + ((s ^ (q & 3)) * 16) + (g & 1) * 8;
            uint2 pk2;
            pk2.x = packbf2(O[mi][ni][0] * is, O[mi][ni][1] * is);
            pk2.y = packbf2(O[mi][ni][2] * is, O[mi][ni][3] * is);
            *reinterpret_cast<uint2*>(reinterpret_cast<char*>(lsP) + byteoff) = pk2;
        }
    }

    // ---- coalesced store: lane reads chunk (q, p), stores 16B ----
    const int qr0 = l >> 2, p = l & 3;
    ushort_t* obase = attn_out + R * 512 + h * 32;
    #pragma unroll
    for (int r = 0; r < 4; ++r) {
        const int q = qr0 + r * 16;
        uint4 row = *reinterpret_cast<const uint4*>(
            reinterpret_cast<const char*>(lsP) + q * 64 + ((p ^ (q & 3)) * 16));
        *reinterpret_cast<uint4*>(
            reinterpret_cast<char*>(obase + (size_t)q * 512) + p * 16) = row;
    }
}

// ---------- launch ----------
extern "C" void kernel_launch(void* const* d_in, const int* in_sizes, int n_in,
                              void* d_out, int out_size, void* d_ws, size_t ws_size,
                              hipStream_t stream)
{
    (void)in_sizes; (void)n_in; (void)out_size; (void)ws_size;
    const float* x     = (const float*)d_in[0];   // (8,64,64,512)
    const float* wqkv  = (const float*)d_in[1];   // (1536,512)
    const float* qb    = (const float*)d_in[2];   // (512)
    const float* vb    = (const float*)d_in[3];   // (512)
    const float* ls    = (const float*)d_in[4];   // (16,1,1,1)
    const float* wproj = (const float*)d_in[5];   // (512,512)
    const float* pb    = (const float*)d_in[6];   // (512)
    float* out = (float*)d_out;

    char* ws = (char*)d_ws;
    ushort_t* xb      = (ushort_t*)(ws);                    // 33,554,432 B
    ushort_t* wqkvb   = (ushort_t*)(ws + 33554432);         //  1,572,864 B
    ushort_t* wprojb  = (ushort_t*)(ws + 35127296);         //    524,288 B
    ushort_t* qkvb    = (ushort_t*)(ws + 35651584);         // 100,663,296 B
    ushort_t* attnb   = (ushort_t*)(ws + 136314880);        // 33,554,432 B
    float*    qkvbias = (float*)   (ws + 169869312);        //      6,144 B

    cvt_f32_bf16<<<16384, 256, 0, stream>>>(x,     xb,     16777216 / 4);
    cvt_f32_bf16<<<768,   256, 0, stream>>>(wqkv,  wqkvb,  786432   / 4);
    cvt_f32_bf16<<<256,   256, 0, stream>>>(wproj, wprojb, 262144   / 4);
    build_qkv_bias<<<6, 256, 0, stream>>>(qb, vb, qkvbias);

    // qkv = x @ Wqkv^T + bias   (M=32768, N=1536, K=512); nwg=3072 (%8==0)
    gemm_bt_2ph<true><<<3072, 256, 0, stream>>>(
        xb, wqkvb, qkvbias, qkvb, MROWS, 3 * DIMC, DIMC, 12);

    // per-window attention (MFMA)
    win_attn_mfma<<<NBATCH * NHEADS * NWIN, 64, 0, stream>>>(qkvb, ls, attnb);

    // out = attn @ Wproj^T + proj_bias  (M=32768, N=512, K=512); nwg=1024
    gemm_bt_2ph<false><<<1024, 256, 0, stream>>>(
        attnb, wprojb, pb, out, MROWS, DIMC, DIMC, 4);
}